// Round 3
// baseline (90.811 us; speedup 1.0000x reference)
//
#include <hip/hip_runtime.h>
#include <math.h>

#define BATCH 16384
#define OUTF  1024
#define INF   1024
#define KPROJ 256
#define MTOT  (BATCH + OUTF)   // 17408

#define NZ_THRESH 0.15f        // ~6.8 sigma of f16 dot error (sigma ~0.022)

typedef unsigned long long u64;
typedef unsigned short     u16;
typedef _Float16           f16;
typedef __attribute__((ext_vector_type(8))) _Float16 f16x8;
typedef __attribute__((ext_vector_type(4))) float    f32x4;

// ---------------------------------------------------------------------------
// prep_p: P (256 x 1024) fp32 -> f16 in MFMA FRAGMENT ORDER.
// Fragment f = (kt*16 + j)*2 + ks holds, for lane = l4*16+l15, the 8 f16
// elements  B[col = j*16+l15][k = kt*64 + ks*32 + l4*8 .. +7].
// gemm then reads each fragment as ONE wave-contiguous 1KB dwordx4 burst.
// Block = one k-chunk c (k = c*8..c*8+7), thread = one col p.
// ---------------------------------------------------------------------------
__global__ __launch_bounds__(256) void prep_p(const float* __restrict__ P,
                                              f16* __restrict__ Bf) {
    const int c = blockIdx.x;      // 0..127
    const int p = threadIdx.x;     // 0..255 (= B col)
    const float4 f0 = *(const float4*)(P + (size_t)p * INF + c * 8);
    const float4 f1 = *(const float4*)(P + (size_t)p * INF + c * 8 + 4);
    const int kt = c >> 3, ks = (c >> 2) & 1, lq = c & 3;
    const int frag = (kt * 16 + (p >> 4)) * 2 + ks;
    const int lane = lq * 16 + (p & 15);
    f16x8 h;
    h[0] = (f16)f0.x; h[1] = (f16)f0.y; h[2] = (f16)f0.z; h[3] = (f16)f0.w;
    h[4] = (f16)f1.x; h[5] = (f16)f1.y; h[6] = (f16)f1.z; h[7] = (f16)f1.w;
    *(f16x8*)(Bf + (size_t)(frag * 64 + lane) * 8) = h;
}

// ---------------------------------------------------------------------------
// K-split sign GEMM. Block = 256 thr = 4 waves, all on the SAME 16 rows.
// Wave w owns K-tiles kb = w*4 .. w*4+3 (K range of 256).
//   1) A slice (16 rows x 256 k) preloaded fp32->f16 into 8 f16x8 regs
//      BEFORE the loop -> K-loop vmem queue is PURE L2 B-fragment loads
//      (no in-order vmcnt mixing with HBM misses).
//   2) 4-iteration K-loop, 32 MFMA + 32 coalesced 1KB B-loads per iter,
//      no barriers, no LDS.
//   3) 2-round LDS tree combines the 4 partial acc sets (3 barriers total);
//      final accs redistributed so each wave epilogues 4 of the 16 j-cols.
// Grid = 1088 blocks = 4352 waves (~16 waves/CU TLP).
// ---------------------------------------------------------------------------
__global__ __launch_bounds__(256, 4) void gemm_signs(const float* __restrict__ X,
                                                     const float* __restrict__ W,
                                                     const f16* __restrict__ Bf,
                                                     const float* __restrict__ Pf,
                                                     u64* __restrict__ cx,
                                                     u64* __restrict__ cw,
                                                     float* __restrict__ xn,
                                                     float* __restrict__ wn) {
    __shared__ f32x4 red[2][16][64];    // 32 KB reduction buffer
    __shared__ float nsq[4][16];
    __shared__ u16 sw[16][16];

    const int t    = threadIdx.x;
    const int wid  = t >> 6, lane = t & 63;
    const int l4   = lane >> 4, l15 = lane & 15;
    const int row0 = blockIdx.x * 16;
    const int kb   = wid * 4;                    // this wave's first K-tile

    const float* Asrc = (row0 < BATCH) ? X + (size_t)row0 * INF
                                       : W + (size_t)(row0 - BATCH) * INF;
    // lane's A source: row l15 of the tile, k-chunk base l4*8
    const float* aPtr = Asrc + (size_t)l15 * INF + l4 * 8;

    // ---- A preload: this wave's 4 K-tiles, converted to f16 fragments ----
    f16x8 af[8];            // af[2i]: ks=0 of tile kb+i, af[2i+1]: ks=1
    float ssq = 0.0f;
#pragma unroll
    for (int i = 0; i < 4; ++i) {
        const float* p = aPtr + (kb + i) * 64;
        float4 q0 = *(const float4*)(p);
        float4 q1 = *(const float4*)(p + 4);
        float4 q2 = *(const float4*)(p + 32);
        float4 q3 = *(const float4*)(p + 36);
        ssq += q0.x * q0.x + q0.y * q0.y + q0.z * q0.z + q0.w * q0.w +
               q1.x * q1.x + q1.y * q1.y + q1.z * q1.z + q1.w * q1.w +
               q2.x * q2.x + q2.y * q2.y + q2.z * q2.z + q2.w * q2.w +
               q3.x * q3.x + q3.y * q3.y + q3.z * q3.z + q3.w * q3.w;
        f16x8 a0, a1;
        a0[0] = (f16)q0.x; a0[1] = (f16)q0.y; a0[2] = (f16)q0.z; a0[3] = (f16)q0.w;
        a0[4] = (f16)q1.x; a0[5] = (f16)q1.y; a0[6] = (f16)q1.z; a0[7] = (f16)q1.w;
        a1[0] = (f16)q2.x; a1[1] = (f16)q2.y; a1[2] = (f16)q2.z; a1[3] = (f16)q2.w;
        a1[4] = (f16)q3.x; a1[5] = (f16)q3.y; a1[6] = (f16)q3.z; a1[7] = (f16)q3.w;
        af[2 * i]     = a0;
        af[2 * i + 1] = a1;
    }

    // ---- K-loop: pure L2 B-fragment loads + MFMA, no barriers ----
    f32x4 acc[16] = {};
    const f16* bk = Bf + (size_t)kb * 16384 + lane * 8;
#pragma unroll
    for (int i = 0; i < 4; ++i) {
        const f16* b = bk + i * 16384;
#pragma unroll
        for (int j = 0; j < 16; ++j) {
            f16x8 b0 = *(const f16x8*)(b + (2 * j) * 512);
            f16x8 b1 = *(const f16x8*)(b + (2 * j + 1) * 512);
            acc[j] = __builtin_amdgcn_mfma_f32_16x16x32_f16(af[2 * i],     b0, acc[j], 0, 0, 0);
            acc[j] = __builtin_amdgcn_mfma_f32_16x16x32_f16(af[2 * i + 1], b1, acc[j], 0, 0, 0);
        }
    }

    // ---- partial row norms (rows lane-private: row = row0 + l15) ----
    ssq += __shfl_xor(ssq, 16, 64);
    ssq += __shfl_xor(ssq, 32, 64);
    if (lane < 16) nsq[wid][l15] = ssq;

    // ---- 2-round LDS reduction of the 4 partial acc sets ----
    if (wid == 1)
#pragma unroll
        for (int j = 0; j < 16; ++j) red[0][j][lane] = acc[j];
    if (wid == 3)
#pragma unroll
        for (int j = 0; j < 16; ++j) red[1][j][lane] = acc[j];
    __syncthreads();
    if (wid == 0)
#pragma unroll
        for (int j = 0; j < 16; ++j) acc[j] += red[0][j][lane];
    if (wid == 2)
#pragma unroll
        for (int j = 0; j < 16; ++j) {
            acc[j] += red[1][j][lane];
            red[1][j][lane] = acc[j];
        }
    if (wid == 1 && lane < 16) {     // finalize norms on an idle wave
        const float s = nsq[0][lane] + nsq[1][lane] + nsq[2][lane] + nsq[3][lane];
        const float n = sqrtf(s) + 1.1920929e-07f;
        const int grow = row0 + lane;
        if (grow < BATCH) xn[grow] = n; else wn[grow - BATCH] = n;
    }
    __syncthreads();
    if (wid == 0)
#pragma unroll
        for (int j = 0; j < 16; ++j) {
            acc[j] += red[1][j][lane];
            red[0][j][lane] = acc[j];
        }
    __syncthreads();

    // ---- distributed epilogue: wave w owns j = w*4 .. w*4+3 ----
    f32x4 facc[4];
#pragma unroll
    for (int jj = 0; jj < 4; ++jj) facc[jj] = red[0][wid * 4 + jj][lane];

#pragma unroll
    for (int jj = 0; jj < 4; ++jj) {
        const int j = wid * 4 + jj;
#pragma unroll
        for (int q = 0; q < 4; ++q) {
            const float v = facc[jj][q];
            int bit = (v >= 0.0f) ? 1 : 0;
            u64 fl = __ballot(fabsf(v) < NZ_THRESH);
            while (fl) {   // rare (~4/wave): whole wave re-dots in fp64
                const int src = __ffsll((long long)fl) - 1;
                fl &= fl - 1;
                const int lrow = ((src >> 4) << 2) + q;
                const int col  = j * 16 + (src & 15);
                const float* xr = Asrc + (size_t)lrow * INF + lane * 16;
                const float* pr = Pf + (size_t)col * INF + lane * 16;
                double s = 0.0;
#pragma unroll
                for (int c4 = 0; c4 < 4; ++c4) {
                    float4 xa = *(const float4*)(xr + c4 * 4);
                    float4 pa = *(const float4*)(pr + c4 * 4);
                    s += (double)xa.x * pa.x + (double)xa.y * pa.y +
                         (double)xa.z * pa.z + (double)xa.w * pa.w;
                }
#pragma unroll
                for (int off = 32; off; off >>= 1) s += __shfl_xor(s, off, 64);
                if (lane == src) bit = (s >= 0.0) ? 1 : 0;
            }
            const u64 b = __ballot(bit != 0);
            if (l15 == 0)
                sw[l4 * 4 + q][j] = (u16)(b >> (l4 * 16));
        }
    }
    __syncthreads();
    if (t < 64) {
        const int r = t >> 2, w = t & 3;
        const u64 val = *(const u64*)&sw[r][w * 4];
        const int grow = row0 + r;
        if (grow < BATCH) cx[(size_t)grow * 4 + w] = val;
        else              cw[(size_t)(grow - BATCH) * 4 + w] = val;
    }
}

// ---------------------------------------------------------------------------
// out[b][m] = xn[b] * wn[m] * cos(pi * popc / 256)
// ---------------------------------------------------------------------------
__global__ __launch_bounds__(256) void popc_out(const u64* __restrict__ cx,
                                                const u64* __restrict__ cw,
                                                const float* __restrict__ xn,
                                                const float* __restrict__ wn,
                                                float* __restrict__ out) {
    __shared__ float lut[257];
    __shared__ u64 cxs[64][4];
    __shared__ float xns[64];
    const int t = threadIdx.x;

    lut[t] = (float)cos((double)t * (3.14159265358979323846 / 256.0));
    if (t == 0) lut[256] = -1.0f;

    const int r0 = blockIdx.x * 64;
    cxs[t >> 2][t & 3] = cx[(size_t)r0 * 4 + t];
    if (t < 64) xns[t] = xn[r0 + t];

    const ulonglong4* cwv4 = (const ulonglong4*)cw;
    ulonglong4 c0 = cwv4[4 * t + 0];
    ulonglong4 c1 = cwv4[4 * t + 1];
    ulonglong4 c2 = cwv4[4 * t + 2];
    ulonglong4 c3 = cwv4[4 * t + 3];
    float4 wnr = ((const float4*)wn)[t];

    __syncthreads();

    float4* outv = (float4*)out;
    const size_t obase = (size_t)r0 * (OUTF / 4) + t;
#pragma unroll 4
    for (int r = 0; r < 64; ++r) {
        const u64 a0 = cxs[r][0], a1 = cxs[r][1], a2 = cxs[r][2], a3 = cxs[r][3];
        const float sx = xns[r];
        float4 o;
        o.x = sx * wnr.x * lut[__popcll(a0 ^ c0.x) + __popcll(a1 ^ c0.y) +
                               __popcll(a2 ^ c0.z) + __popcll(a3 ^ c0.w)];
        o.y = sx * wnr.y * lut[__popcll(a0 ^ c1.x) + __popcll(a1 ^ c1.y) +
                               __popcll(a2 ^ c1.z) + __popcll(a3 ^ c1.w)];
        o.z = sx * wnr.z * lut[__popcll(a0 ^ c2.x) + __popcll(a1 ^ c2.y) +
                               __popcll(a2 ^ c2.z) + __popcll(a3 ^ c2.w)];
        o.w = sx * wnr.w * lut[__popcll(a0 ^ c3.x) + __popcll(a1 ^ c3.y) +
                               __popcll(a2 ^ c3.z) + __popcll(a3 ^ c3.w)];
        outv[obase + (size_t)r * (OUTF / 4)] = o;
    }
}

extern "C" void kernel_launch(void* const* d_in, const int* in_sizes, int n_in,
                              void* d_out, int out_size, void* d_ws, size_t ws_size,
                              hipStream_t stream) {
    const float* x = (const float*)d_in[0];
    const float* w = (const float*)d_in[1];
    const float* P = (const float*)d_in[2];
    float* out = (float*)d_out;

    char* ws = (char*)d_ws;
    f16*  Bf = (f16*)ws;                         // +0        (524288 B)
    u64*  cx = (u64*)(ws + 524288);              // +524288   (524288 B)
    u64*  cw = (u64*)(ws + 1048576);             // +1048576  (32768 B)
    float* xn = (float*)(ws + 1081344);          // +1081344  (65536 B)
    float* wn = (float*)(ws + 1146880);          // +1146880  (4096 B)

    prep_p<<<128, 256, 0, stream>>>(P, Bf);

    gemm_signs<<<MTOT / 16, 256, 0, stream>>>(x, w, Bf, P, cx, cw, xn, wn);

    popc_out<<<BATCH / 64, 256, 0, stream>>>(cx, cw, xn, wn, out);
}

// Round 4
// 75.950 us; speedup vs baseline: 1.1957x; 1.1957x over previous
//
#include <hip/hip_runtime.h>
#include <math.h>

#define BATCH 16384
#define OUTF  1024
#define INF   1024
#define KPROJ 256
#define MTOT  (BATCH + OUTF)   // 17408

#define NZ_THRESH 0.15f        // ~6.8 sigma of f16 dot error (sigma ~0.022)

typedef unsigned long long u64;
typedef unsigned short     u16;
typedef _Float16           f16;
typedef __attribute__((ext_vector_type(8))) _Float16 f16x8;
typedef __attribute__((ext_vector_type(4))) float    f32x4;

#define SCHED0() __builtin_amdgcn_sched_barrier(0)

// ---------------------------------------------------------------------------
// prep_p: P (256 x 1024) fp32 -> f16 in MFMA FRAGMENT ORDER.
// Fragment f = (kt*16 + j)*2 + ks holds, for lane = l4*16+l15, the 8 f16
// elements  B[col = j*16+l15][k = kt*64 + ks*32 + l4*8 .. +7].
// gemm then reads each fragment as ONE wave-contiguous 1KB dwordx4 burst.
// ---------------------------------------------------------------------------
__global__ __launch_bounds__(256) void prep_p(const float* __restrict__ P,
                                              f16* __restrict__ Bf) {
    const int c = blockIdx.x;      // 0..127
    const int p = threadIdx.x;     // 0..255 (= B col)
    const float4 f0 = *(const float4*)(P + (size_t)p * INF + c * 8);
    const float4 f1 = *(const float4*)(P + (size_t)p * INF + c * 8 + 4);
    const int kt = c >> 3, ks = (c >> 2) & 1, lq = c & 3;
    const int frag = (kt * 16 + (p >> 4)) * 2 + ks;
    const int lane = lq * 16 + (p & 15);
    f16x8 h;
    h[0] = (f16)f0.x; h[1] = (f16)f0.y; h[2] = (f16)f0.z; h[3] = (f16)f0.w;
    h[4] = (f16)f1.x; h[5] = (f16)f1.y; h[6] = (f16)f1.z; h[7] = (f16)f1.w;
    *(f16x8*)(Bf + (size_t)(frag * 64 + lane) * 8) = h;
}

// ---------------------------------------------------------------------------
// K-split sign GEMM with DECORRELATED B streams + explicit 3-deep register
// pipeline.  Block = 4 waves on the same 16 rows; wave w owns K-quarter
// kb = ((w + blockIdx) & 3) * 4.  acc slot s holds column-block
// jc = (s + roff) & 15 where roff = (blockIdx*5) & 15  -> runtime addresses,
// compile-time register indices.  Chip-wide, B-fragment requests are spread
// over 64 phase classes instead of one lockstep stream (anti L2-bank-camp).
// B K-loop: 16 fully-unrolled batches (8 x 1KB coalesced L2 loads + 8 MFMA),
// 3 rotating named buffer sets, counted s_waitcnt vmcnt(16): 24 loads/wave
// in flight, pure-L2 queue (A is preloaded & drained before the loop).
// ---------------------------------------------------------------------------
__global__ __launch_bounds__(256, 2) void gemm_signs(const float* __restrict__ X,
                                                     const float* __restrict__ W,
                                                     const f16* __restrict__ Bf,
                                                     const float* __restrict__ Pf,
                                                     u64* __restrict__ cx,
                                                     u64* __restrict__ cw,
                                                     float* __restrict__ xn,
                                                     float* __restrict__ wn) {
    __shared__ f32x4 red[2][16][64];    // 32 KB reduction buffer
    __shared__ float nsq[4][16];
    __shared__ u16 sw[16][16];

    const int t    = threadIdx.x;
    const int wid  = t >> 6, lane = t & 63;
    const int l4   = lane >> 4, l15 = lane & 15;
    const int row0 = blockIdx.x * 16;
    const int kb   = ((wid + blockIdx.x) & 3) * 4;   // K-quarter rotation
    const int roff = (blockIdx.x * 5) & 15;          // column rotation

    const float* Asrc = (row0 < BATCH) ? X + (size_t)row0 * INF
                                       : W + (size_t)(row0 - BATCH) * INF;
    const float* aPtr = Asrc + (size_t)l15 * INF + l4 * 8;

    // ---- A preload: this wave's 4 K-tiles, fp32 -> f16 fragments ----
    f16x8 af[8];            // af[2i]: ks=0 of tile kb+i, af[2i+1]: ks=1
    float ssq = 0.0f;
#pragma unroll
    for (int i = 0; i < 4; ++i) {
        const float* p = aPtr + (kb + i) * 64;
        float4 q0 = *(const float4*)(p);
        float4 q1 = *(const float4*)(p + 4);
        float4 q2 = *(const float4*)(p + 32);
        float4 q3 = *(const float4*)(p + 36);
        ssq += q0.x * q0.x + q0.y * q0.y + q0.z * q0.z + q0.w * q0.w +
               q1.x * q1.x + q1.y * q1.y + q1.z * q1.z + q1.w * q1.w +
               q2.x * q2.x + q2.y * q2.y + q2.z * q2.z + q2.w * q2.w +
               q3.x * q3.x + q3.y * q3.y + q3.z * q3.z + q3.w * q3.w;
        f16x8 a0, a1;
        a0[0] = (f16)q0.x; a0[1] = (f16)q0.y; a0[2] = (f16)q0.z; a0[3] = (f16)q0.w;
        a0[4] = (f16)q1.x; a0[5] = (f16)q1.y; a0[6] = (f16)q1.z; a0[7] = (f16)q1.w;
        a1[0] = (f16)q2.x; a1[1] = (f16)q2.y; a1[2] = (f16)q2.z; a1[3] = (f16)q2.w;
        a1[4] = (f16)q3.x; a1[5] = (f16)q3.y; a1[6] = (f16)q3.z; a1[7] = (f16)q3.w;
        af[2 * i]     = a0;
        af[2 * i + 1] = a1;
    }

    // f16-element offsets of each acc slot's column fragment pair
    int joff[16];
#pragma unroll
    for (int s = 0; s < 16; ++s) joff[s] = ((s + roff) & 15) * 1024;

    f32x4 acc[16] = {};
    const f16* bq = Bf + lane * 8;

    f16x8 bA0, bA1, bA2, bA3, bA4, bA5, bA6, bA7;
    f16x8 bB0, bB1, bB2, bB3, bB4, bB5, bB6, bB7;
    f16x8 bC0, bC1, bC2, bC3, bC4, bC5, bC6, bC7;

#define BLOAD(BUF, G)                                                         \
    {                                                                         \
        const f16* bt_ = bq + (size_t)(kb + ((G) >> 2)) * 16384;              \
        BUF##0 = *(const f16x8*)(bt_ + joff[((G) & 3) * 4 + 0]);              \
        BUF##1 = *(const f16x8*)(bt_ + joff[((G) & 3) * 4 + 0] + 512);        \
        BUF##2 = *(const f16x8*)(bt_ + joff[((G) & 3) * 4 + 1]);              \
        BUF##3 = *(const f16x8*)(bt_ + joff[((G) & 3) * 4 + 1] + 512);        \
        BUF##4 = *(const f16x8*)(bt_ + joff[((G) & 3) * 4 + 2]);              \
        BUF##5 = *(const f16x8*)(bt_ + joff[((G) & 3) * 4 + 2] + 512);        \
        BUF##6 = *(const f16x8*)(bt_ + joff[((G) & 3) * 4 + 3]);              \
        BUF##7 = *(const f16x8*)(bt_ + joff[((G) & 3) * 4 + 3] + 512);        \
    }

#define BMFMA(BUF, G)                                                         \
    {                                                                         \
        acc[((G) & 3) * 4 + 0] = __builtin_amdgcn_mfma_f32_16x16x32_f16(      \
            af[2 * ((G) >> 2)],     BUF##0, acc[((G) & 3) * 4 + 0], 0, 0, 0); \
        acc[((G) & 3) * 4 + 0] = __builtin_amdgcn_mfma_f32_16x16x32_f16(      \
            af[2 * ((G) >> 2) + 1], BUF##1, acc[((G) & 3) * 4 + 0], 0, 0, 0); \
        acc[((G) & 3) * 4 + 1] = __builtin_amdgcn_mfma_f32_16x16x32_f16(      \
            af[2 * ((G) >> 2)],     BUF##2, acc[((G) & 3) * 4 + 1], 0, 0, 0); \
        acc[((G) & 3) * 4 + 1] = __builtin_amdgcn_mfma_f32_16x16x32_f16(      \
            af[2 * ((G) >> 2) + 1], BUF##3, acc[((G) & 3) * 4 + 1], 0, 0, 0); \
        acc[((G) & 3) * 4 + 2] = __builtin_amdgcn_mfma_f32_16x16x32_f16(      \
            af[2 * ((G) >> 2)],     BUF##4, acc[((G) & 3) * 4 + 2], 0, 0, 0); \
        acc[((G) & 3) * 4 + 2] = __builtin_amdgcn_mfma_f32_16x16x32_f16(      \
            af[2 * ((G) >> 2) + 1], BUF##5, acc[((G) & 3) * 4 + 2], 0, 0, 0); \
        acc[((G) & 3) * 4 + 3] = __builtin_amdgcn_mfma_f32_16x16x32_f16(      \
            af[2 * ((G) >> 2)],     BUF##6, acc[((G) & 3) * 4 + 3], 0, 0, 0); \
        acc[((G) & 3) * 4 + 3] = __builtin_amdgcn_mfma_f32_16x16x32_f16(      \
            af[2 * ((G) >> 2) + 1], BUF##7, acc[((G) & 3) * 4 + 3], 0, 0, 0); \
    }

#define STEPL(BUF, G, VM, GN)                                                 \
    asm volatile("s_waitcnt vmcnt(" VM ")" ::: "memory");                     \
    SCHED0();                                                                 \
    BMFMA(BUF, G);                                                            \
    BLOAD(BUF, GN);                                                           \
    SCHED0();

#define STEPN(BUF, G, VM)                                                     \
    asm volatile("s_waitcnt vmcnt(" VM ")" ::: "memory");                     \
    SCHED0();                                                                 \
    BMFMA(BUF, G);                                                            \
    SCHED0();

    // prologue: 3 batches in flight
    BLOAD(bA, 0);
    BLOAD(bB, 1);
    BLOAD(bC, 2);
    STEPL(bA, 0,  "16", 3);
    STEPL(bB, 1,  "16", 4);
    STEPL(bC, 2,  "16", 5);
    STEPL(bA, 3,  "16", 6);
    STEPL(bB, 4,  "16", 7);
    STEPL(bC, 5,  "16", 8);
    STEPL(bA, 6,  "16", 9);
    STEPL(bB, 7,  "16", 10);
    STEPL(bC, 8,  "16", 11);
    STEPL(bA, 9,  "16", 12);
    STEPL(bB, 10, "16", 13);
    STEPL(bC, 11, "16", 14);
    STEPL(bA, 12, "16", 15);
    STEPN(bB, 13, "16");
    STEPN(bC, 14, "8");
    STEPN(bA, 15, "0");

    // ---- partial row norms (rows lane-private: row = row0 + l15) ----
    ssq += __shfl_xor(ssq, 16, 64);
    ssq += __shfl_xor(ssq, 32, 64);
    if (lane < 16) nsq[wid][l15] = ssq;

    // ---- 2-round LDS reduction of the 4 partial acc sets ----
    if (wid == 1)
#pragma unroll
        for (int j = 0; j < 16; ++j) red[0][j][lane] = acc[j];
    if (wid == 3)
#pragma unroll
        for (int j = 0; j < 16; ++j) red[1][j][lane] = acc[j];
    __syncthreads();
    if (wid == 0)
#pragma unroll
        for (int j = 0; j < 16; ++j) acc[j] += red[0][j][lane];
    if (wid == 2)
#pragma unroll
        for (int j = 0; j < 16; ++j) {
            acc[j] += red[1][j][lane];
            red[1][j][lane] = acc[j];
        }
    if (wid == 1 && lane < 16) {     // finalize norms on an idle wave
        const float s = nsq[0][lane] + nsq[1][lane] + nsq[2][lane] + nsq[3][lane];
        const float n = sqrtf(s) + 1.1920929e-07f;
        const int grow = row0 + lane;
        if (grow < BATCH) xn[grow] = n; else wn[grow - BATCH] = n;
    }
    __syncthreads();
    if (wid == 0)
#pragma unroll
        for (int j = 0; j < 16; ++j) {
            acc[j] += red[1][j][lane];
            red[0][j][lane] = acc[j];
        }
    __syncthreads();

    // ---- distributed epilogue: wave w owns acc slots s = w*4 .. w*4+3,
    //      which hold column-block jc = (s + roff) & 15 ----
    f32x4 facc[4];
#pragma unroll
    for (int jj = 0; jj < 4; ++jj) facc[jj] = red[0][wid * 4 + jj][lane];

#pragma unroll
    for (int jj = 0; jj < 4; ++jj) {
        const int j = (wid * 4 + jj + roff) & 15;    // actual column block
#pragma unroll
        for (int q = 0; q < 4; ++q) {
            const float v = facc[jj][q];
            int bit = (v >= 0.0f) ? 1 : 0;
            u64 fl = __ballot(fabsf(v) < NZ_THRESH);
            while (fl) {   // rare (~4/wave): whole wave re-dots in fp64
                const int src = __ffsll((long long)fl) - 1;
                fl &= fl - 1;
                const int lrow = ((src >> 4) << 2) + q;
                const int col  = j * 16 + (src & 15);
                const float* xr = Asrc + (size_t)lrow * INF + lane * 16;
                const float* pr = Pf + (size_t)col * INF + lane * 16;
                double s = 0.0;
#pragma unroll
                for (int c4 = 0; c4 < 4; ++c4) {
                    float4 xa = *(const float4*)(xr + c4 * 4);
                    float4 pa = *(const float4*)(pr + c4 * 4);
                    s += (double)xa.x * pa.x + (double)xa.y * pa.y +
                         (double)xa.z * pa.z + (double)xa.w * pa.w;
                }
#pragma unroll
                for (int off = 32; off; off >>= 1) s += __shfl_xor(s, off, 64);
                if (lane == src) bit = (s >= 0.0) ? 1 : 0;
            }
            const u64 b = __ballot(bit != 0);
            if (l15 == 0)
                sw[l4 * 4 + q][j] = (u16)(b >> (l4 * 16));
        }
    }
    __syncthreads();
    if (t < 64) {
        const int r = t >> 2, w = t & 3;
        const u64 val = *(const u64*)&sw[r][w * 4];
        const int grow = row0 + r;
        if (grow < BATCH) cx[(size_t)grow * 4 + w] = val;
        else              cw[(size_t)(grow - BATCH) * 4 + w] = val;
    }
}

// ---------------------------------------------------------------------------
// out[b][m] = xn[b] * wn[m] * cos(pi * popc / 256)
// ---------------------------------------------------------------------------
__global__ __launch_bounds__(256) void popc_out(const u64* __restrict__ cx,
                                                const u64* __restrict__ cw,
                                                const float* __restrict__ xn,
                                                const float* __restrict__ wn,
                                                float* __restrict__ out) {
    __shared__ float lut[257];
    __shared__ u64 cxs[64][4];
    __shared__ float xns[64];
    const int t = threadIdx.x;

    lut[t] = (float)cos((double)t * (3.14159265358979323846 / 256.0));
    if (t == 0) lut[256] = -1.0f;

    const int r0 = blockIdx.x * 64;
    cxs[t >> 2][t & 3] = cx[(size_t)r0 * 4 + t];
    if (t < 64) xns[t] = xn[r0 + t];

    const ulonglong4* cwv4 = (const ulonglong4*)cw;
    ulonglong4 c0 = cwv4[4 * t + 0];
    ulonglong4 c1 = cwv4[4 * t + 1];
    ulonglong4 c2 = cwv4[4 * t + 2];
    ulonglong4 c3 = cwv4[4 * t + 3];
    float4 wnr = ((const float4*)wn)[t];

    __syncthreads();

    float4* outv = (float4*)out;
    const size_t obase = (size_t)r0 * (OUTF / 4) + t;
#pragma unroll 4
    for (int r = 0; r < 64; ++r) {
        const u64 a0 = cxs[r][0], a1 = cxs[r][1], a2 = cxs[r][2], a3 = cxs[r][3];
        const float sx = xns[r];
        float4 o;
        o.x = sx * wnr.x * lut[__popcll(a0 ^ c0.x) + __popcll(a1 ^ c0.y) +
                               __popcll(a2 ^ c0.z) + __popcll(a3 ^ c0.w)];
        o.y = sx * wnr.y * lut[__popcll(a0 ^ c1.x) + __popcll(a1 ^ c1.y) +
                               __popcll(a2 ^ c1.z) + __popcll(a3 ^ c1.w)];
        o.z = sx * wnr.z * lut[__popcll(a0 ^ c2.x) + __popcll(a1 ^ c2.y) +
                               __popcll(a2 ^ c2.z) + __popcll(a3 ^ c2.w)];
        o.w = sx * wnr.w * lut[__popcll(a0 ^ c3.x) + __popcll(a1 ^ c3.y) +
                               __popcll(a2 ^ c3.z) + __popcll(a3 ^ c3.w)];
        outv[obase + (size_t)r * (OUTF / 4)] = o;
    }
}

extern "C" void kernel_launch(void* const* d_in, const int* in_sizes, int n_in,
                              void* d_out, int out_size, void* d_ws, size_t ws_size,
                              hipStream_t stream) {
    const float* x = (const float*)d_in[0];
    const float* w = (const float*)d_in[1];
    const float* P = (const float*)d_in[2];
    float* out = (float*)d_out;

    char* ws = (char*)d_ws;
    f16*  Bf = (f16*)ws;                         // +0        (524288 B)
    u64*  cx = (u64*)(ws + 524288);              // +524288   (524288 B)
    u64*  cw = (u64*)(ws + 1048576);             // +1048576  (32768 B)
    float* xn = (float*)(ws + 1081344);          // +1081344  (65536 B)
    float* wn = (float*)(ws + 1146880);          // +1146880  (4096 B)

    prep_p<<<128, 256, 0, stream>>>(P, Bf);

    gemm_signs<<<MTOT / 16, 256, 0, stream>>>(x, w, Bf, P, cx, cw, xn, wn);

    popc_out<<<BATCH / 64, 256, 0, stream>>>(cx, cw, xn, wn, out);
}